// Round 1
// baseline (89.839 us; speedup 1.0000x reference)
//
#include <hip/hip_runtime.h>
#include <math.h>

// Problem geometry (fixed by the reference):
// inputs: (8, 1, 64, 256, 256) f32 -> u: (B=8, T=64, NY=256, NX=256)
// residual grid: (B, TOUT=62, NY, NX); center plane is t+1.
#define B_   8
#define T_   64
#define NY_  256
#define NX_  256
#define TOUT_ 62
#define XG_  (NX_ / 4)                       // 64 x-groups of 4
#define TOTAL_ (B_ * TOUT_ * NY_ * XG_)      // 8,126,464 groups

#define NBLOCKS 2048
#define NTHREADS 256

__global__ __launch_bounds__(NTHREADS)
void pinn_residual_partial(const float* __restrict__ u, float* __restrict__ partial) {
    const float inv_dh2 = 1.0f / 25.0f;                 // 1/DH^2
    const float kdt     = 250000.0f / 4840000.0f;       // (1/DT^2) / C^2

    int tid    = blockIdx.x * NTHREADS + threadIdx.x;
    int stride = NBLOCKS * NTHREADS;

    float s = 0.0f;
    for (int idx = tid; idx < TOTAL_; idx += stride) {
        int xg = idx & (XG_ - 1);
        int y  = (idx >> 6) & (NY_ - 1);
        int r  = idx >> 14;          // r = b*62 + t, r < 496
        int t  = r % TOUT_;
        int b  = r / TOUT_;
        int x0 = xg * 4;

        // center plane: u[b][t+1][y][x0..x0+3]
        const float* base = u + (((long long)b * T_ + (t + 1)) * NY_ + y) * NX_ + x0;
        float4 c  = *(const float4*)base;
        float  cl = (x0 > 0)         ? base[-1] : 0.0f;   // x zero-pad
        float  cr = (x0 + 4 < NX_)   ? base[4]  : 0.0f;
        float4 zero4 = make_float4(0.0f, 0.0f, 0.0f, 0.0f);
        float4 ym = (y > 0)        ? *(const float4*)(base - NX_) : zero4;  // y zero-pad
        float4 yp = (y < NY_ - 1)  ? *(const float4*)(base + NX_) : zero4;

        // time stencil: u[b][t][y][...] and u[b][t+2][y][...]  (t dim NOT padded)
        const float* tbase = u + (((long long)b * T_ + t) * NY_ + y) * NX_ + x0;
        float4 tm = *(const float4*)tbase;
        float4 tp = *(const float4*)(tbase + 2LL * NY_ * NX_);

        float cc[4]  = {c.x,  c.y,  c.z,  c.w};
        float lft[4] = {cl,   c.x,  c.y,  c.z};
        float rgt[4] = {c.y,  c.z,  c.w,  cr};
        float ymm[4] = {ym.x, ym.y, ym.z, ym.w};
        float ypp[4] = {yp.x, yp.y, yp.z, yp.w};
        float tmm[4] = {tm.x, tm.y, tm.z, tm.w};
        float tpp[4] = {tp.x, tp.y, tp.z, tp.w};

        #pragma unroll
        for (int i = 0; i < 4; ++i) {
            float lap = (lft[i] + rgt[i] + ymm[i] + ypp[i] - 4.0f * cc[i]) * inv_dh2;
            float dtt = (tmm[i] - 2.0f * cc[i] + tpp[i]) * kdt;
            float res = lap - dtt;
            s = fmaf(res, res, s);
        }
    }

    // wave64 shuffle reduction
    #pragma unroll
    for (int off = 32; off > 0; off >>= 1)
        s += __shfl_down(s, off, 64);

    __shared__ float lds[NTHREADS / 64];
    int lane = threadIdx.x & 63;
    int wid  = threadIdx.x >> 6;
    if (lane == 0) lds[wid] = s;
    __syncthreads();
    if (threadIdx.x == 0) {
        float bs = 0.0f;
        #pragma unroll
        for (int w = 0; w < NTHREADS / 64; ++w) bs += lds[w];
        partial[blockIdx.x] = bs;   // every slot written every launch: no init needed
    }
}

__global__ __launch_bounds__(NTHREADS)
void pinn_finalize(const float* __restrict__ partial, float* __restrict__ out) {
    float s = 0.0f;
    for (int i = threadIdx.x; i < NBLOCKS; i += NTHREADS)
        s += partial[i];
    #pragma unroll
    for (int off = 32; off > 0; off >>= 1)
        s += __shfl_down(s, off, 64);
    __shared__ float lds[NTHREADS / 64];
    int lane = threadIdx.x & 63;
    int wid  = threadIdx.x >> 6;
    if (lane == 0) lds[wid] = s;
    __syncthreads();
    if (threadIdx.x == 0) {
        float bs = 0.0f;
        #pragma unroll
        for (int w = 0; w < NTHREADS / 64; ++w) bs += lds[w];
        out[0] = sqrtf(bs);
    }
}

extern "C" void kernel_launch(void* const* d_in, const int* in_sizes, int n_in,
                              void* d_out, int out_size, void* d_ws, size_t ws_size,
                              hipStream_t stream) {
    const float* u = (const float*)d_in[0];
    float* partial = (float*)d_ws;          // NBLOCKS floats = 8 KiB of workspace
    float* out     = (float*)d_out;

    pinn_residual_partial<<<NBLOCKS, NTHREADS, 0, stream>>>(u, partial);
    pinn_finalize<<<1, NTHREADS, 0, stream>>>(partial, out);
}

// Round 2
// 40.998 us; speedup vs baseline: 2.1913x; 2.1913x over previous
//
#include <hip/hip_runtime.h>
#include <math.h>

// Geometry: u is (B=8, T=64, NY=256, NX=256) f32.
// Residual grid: (B, TOUT=62, NY, NX), center plane t+1, x/y zero-padded, t not padded.
#define B_    8
#define T_    64
#define NY_   256
#define NX_   256
#define TOUT_ 62
#define PS_   (NY_ * NX_)      // plane stride in elements

// One wave = one full x-row (64 lanes x float4 = 256) at fixed (b, y, t-chunk).
// t-chunks: 7 chunks of 8 steps + 1 chunk of 6 steps = 62.
#define TCHUNKS 8
#define NWAVES  (B_ * NY_ * TCHUNKS)       // 16384
#define NTHREADS 256
#define NBLOCKS (NWAVES / 4)               // 4096 blocks of 4 waves

__device__ __forceinline__ float4 loadf4(const float* p) { return *(const float4*)p; }

template <int LEN>
__device__ __forceinline__ float chunk_accum(const float* __restrict__ u,
                                             int b, int y, int t0, int lane) {
    const float inv_dh2 = 0.04f;                       // 1/DH^2
    const float kdt     = 250000.0f / 4840000.0f;      // (1/DT^2)/C^2

    // y zero-pad: clamp the address (always a valid load), zero via mask-mul.
    const float my_m = (y > 0)        ? 1.0f : 0.0f;
    const float my_p = (y < NY_ - 1)  ? 1.0f : 0.0f;
    const int   ym_off = (y > 0)       ? -NX_ : 0;
    const int   yp_off = (y < NY_ - 1) ?  NX_ : 0;
    // x zero-pad: shfl brings own value at the wave edge; mask it to zero.
    const float xl_m = (lane > 0)  ? 1.0f : 0.0f;
    const float xr_m = (lane < 63) ? 1.0f : 0.0f;

    const float* row0 = u + (((size_t)b * T_ + t0) * NY_ + y) * NX_ + lane * 4;

    // Preload: tm = center row of plane t0; c-plane rows of t0+1.
    float4 tmr = loadf4(row0);
    const float* c1 = row0 + PS_;
    float4 cm = loadf4(c1 + ym_off);
    float4 cc = loadf4(c1);
    float4 cp = loadf4(c1 + yp_off);
    cm.x *= my_m; cm.y *= my_m; cm.z *= my_m; cm.w *= my_m;
    cp.x *= my_p; cp.y *= my_p; cp.z *= my_p; cp.w *= my_p;

    float acc = 0.0f;
    const float* n = row0 + 2 * PS_;
    #pragma unroll
    for (int k = 0; k < LEN; ++k) {
        // New plane t0+2+k: rows y-1, y, y+1 (only new data this step).
        float4 nm = loadf4(n + ym_off);
        float4 nc = loadf4(n);
        float4 np = loadf4(n + yp_off);
        nm.x *= my_m; nm.y *= my_m; nm.z *= my_m; nm.w *= my_m;
        np.x *= my_p; np.y *= my_p; np.z *= my_p; np.w *= my_p;

        // x-neighbors of center row via cross-lane shuffle.
        float cl = __shfl_up(cc.w, 1, 64) * xl_m;
        float cr = __shfl_down(cc.x, 1, 64) * xr_m;

        float l0 = cl,   l1 = cc.x, l2 = cc.y, l3 = cc.z;
        float r0 = cc.y, r1 = cc.z, r2 = cc.w, r3 = cr;

        {
            float lap = (l0 + r0 + cm.x + cp.x - 4.0f * cc.x) * inv_dh2;
            float dtt = (tmr.x - 2.0f * cc.x + nc.x) * kdt;
            float res = lap - dtt;
            acc = fmaf(res, res, acc);
        }
        {
            float lap = (l1 + r1 + cm.y + cp.y - 4.0f * cc.y) * inv_dh2;
            float dtt = (tmr.y - 2.0f * cc.y + nc.y) * kdt;
            float res = lap - dtt;
            acc = fmaf(res, res, acc);
        }
        {
            float lap = (l2 + r2 + cm.z + cp.z - 4.0f * cc.z) * inv_dh2;
            float dtt = (tmr.z - 2.0f * cc.z + nc.z) * kdt;
            float res = lap - dtt;
            acc = fmaf(res, res, acc);
        }
        {
            float lap = (l3 + r3 + cm.w + cp.w - 4.0f * cc.w) * inv_dh2;
            float dtt = (tmr.w - 2.0f * cc.w + nc.w) * kdt;
            float res = lap - dtt;
            acc = fmaf(res, res, acc);
        }

        // Roll planes: t <- t+1.
        tmr = cc; cm = nm; cc = nc; cp = np;
        n += PS_;
    }
    return acc;
}

__global__ __launch_bounds__(NTHREADS)
void pinn_residual_partial(const float* __restrict__ u, float* __restrict__ partial) {
    const int lane = threadIdx.x & 63;
    const int w    = threadIdx.x >> 6;
    const int wid  = blockIdx.x * 4 + w;     // 0..16383
    // y fastest within a block -> adjacent waves share y+-1 rows in L1.
    const int y  = wid & (NY_ - 1);
    const int tc = (wid >> 8) & (TCHUNKS - 1);
    const int b  = wid >> 11;
    const int t0 = tc * 8;

    float s;
    if (tc < 7) s = chunk_accum<8>(u, b, y, t0, lane);
    else        s = chunk_accum<6>(u, b, y, t0, lane);

    // wave64 reduction
    #pragma unroll
    for (int off = 32; off > 0; off >>= 1)
        s += __shfl_down(s, off, 64);

    __shared__ float lds[NTHREADS / 64];
    if (lane == 0) lds[w] = s;
    __syncthreads();
    if (threadIdx.x == 0) {
        float bs = 0.0f;
        #pragma unroll
        for (int q = 0; q < NTHREADS / 64; ++q) bs += lds[q];
        partial[blockIdx.x] = bs;   // every slot written every launch
    }
}

__global__ __launch_bounds__(NTHREADS)
void pinn_finalize(const float* __restrict__ partial, float* __restrict__ out) {
    float s = 0.0f;
    for (int i = threadIdx.x; i < NBLOCKS; i += NTHREADS)
        s += partial[i];
    #pragma unroll
    for (int off = 32; off > 0; off >>= 1)
        s += __shfl_down(s, off, 64);
    __shared__ float lds[NTHREADS / 64];
    int lane = threadIdx.x & 63;
    int wid  = threadIdx.x >> 6;
    if (lane == 0) lds[wid] = s;
    __syncthreads();
    if (threadIdx.x == 0) {
        float bs = 0.0f;
        #pragma unroll
        for (int q = 0; q < NTHREADS / 64; ++q) bs += lds[q];
        out[0] = sqrtf(bs);
    }
}

extern "C" void kernel_launch(void* const* d_in, const int* in_sizes, int n_in,
                              void* d_out, int out_size, void* d_ws, size_t ws_size,
                              hipStream_t stream) {
    const float* u = (const float*)d_in[0];
    float* partial = (float*)d_ws;           // NBLOCKS floats = 16 KiB scratch
    float* out     = (float*)d_out;

    pinn_residual_partial<<<NBLOCKS, NTHREADS, 0, stream>>>(u, partial);
    pinn_finalize<<<1, NTHREADS, 0, stream>>>(partial, out);
}

// Round 3
// 33.989 us; speedup vs baseline: 2.6431x; 1.2062x over previous
//
#include <hip/hip_runtime.h>
#include <math.h>

// u: (B=8, T=64, NY=256, NX=256) f32. Residual: (B, 62, NY, NX), center t+1.
// x/y zero-padded, t not padded. Output: sqrt(sum(res^2)).
#define B_    8
#define T_    64
#define NY_   256
#define NX_   256
#define PS_   (NY_ * NX_)

// One wave = YB consecutive y-rows x full x-row (64 lanes x float4 = 256).
#define YB_     4
#define NSTRIP  (NY_ / YB_)                 // 64 strips
#define TCHUNKS 8                           // 7 chunks of 8 t-steps + 1 of 6
#define NWAVES  (B_ * NSTRIP * TCHUNKS)     // 4096 waves = 16/CU
#define NTHREADS 256
#define NBLOCKS  (NWAVES / 4)               // 1024 blocks

__device__ __forceinline__ float4 loadf4(const float* p) { return *(const float4*)p; }

template <int LEN>
__device__ __forceinline__ float strip_accum(const float* __restrict__ u,
                                             int b, int ys, int t0, int lane) {
    const float a   = 0.04f;                        // 1/DH^2
    const float kdt = 250000.0f / 4840000.0f;       // (1/DT^2)/C^2
    const float k2  = 2.0f * kdt - 4.0f * a;        // coeff of center

    const int y0 = ys * YB_;
    const float m0 = (ys > 0)           ? 1.0f : 0.0f;   // row y0-1 validity
    const float m5 = (ys < NSTRIP - 1)  ? 1.0f : 0.0f;   // row y0+YB validity
    const float xl = (lane > 0)  ? 1.0f : 0.0f;
    const float xr = (lane < 63) ? 1.0f : 0.0f;

    // Row byte-offsets (clamped; boundary rows zeroed via mask-mul).
    int yoff[YB_ + 2];
    #pragma unroll
    for (int j = 0; j < YB_ + 2; ++j) {
        int y = y0 - 1 + j;
        y = y < 0 ? 0 : (y > NY_ - 1 ? NY_ - 1 : y);
        yoff[j] = y * NX_;
    }

    const float* pl = u + ((size_t)b * T_ + t0) * PS_ + lane * 4;

    // Preload: tm = rows y0..y0+3 of plane t0; c = rows y0-1..y0+4 of plane t0+1.
    float4 tm[YB_], c[YB_ + 2];
    #pragma unroll
    for (int i = 0; i < YB_; ++i) tm[i] = loadf4(pl + yoff[i + 1]);
    const float* p1 = pl + PS_;
    #pragma unroll
    for (int j = 0; j < YB_ + 2; ++j) c[j] = loadf4(p1 + yoff[j]);
    c[0].x *= m0; c[0].y *= m0; c[0].z *= m0; c[0].w *= m0;
    c[YB_+1].x *= m5; c[YB_+1].y *= m5; c[YB_+1].z *= m5; c[YB_+1].w *= m5;

    float acc = 0.0f;
    const float* pn = pl + 2 * PS_;
    #pragma unroll
    for (int k = 0; k < LEN; ++k) {
        // New plane t0+2+k: rows y0-1..y0+4.
        float4 nn[YB_ + 2];
        #pragma unroll
        for (int j = 0; j < YB_ + 2; ++j) nn[j] = loadf4(pn + yoff[j]);
        nn[0].x *= m0; nn[0].y *= m0; nn[0].z *= m0; nn[0].w *= m0;
        nn[YB_+1].x *= m5; nn[YB_+1].y *= m5; nn[YB_+1].z *= m5; nn[YB_+1].w *= m5;

        #pragma unroll
        for (int i = 0; i < YB_; ++i) {
            float4 ctr = c[i + 1], up = c[i], dn = c[i + 2];
            float4 t = tm[i], nf = nn[i + 1];
            float cl = __shfl_up(ctr.w, 1, 64) * xl;
            float cr = __shfl_down(ctr.x, 1, 64) * xr;

            // res = (l+r+up+dn)*a + (tm+tp)*(-kdt) + c*(2kdt-4a)
            {
                float s = cl + ctr.y + up.x + dn.x;
                float r = fmaf(s, a, fmaf(t.x + nf.x, -kdt, ctr.x * k2));
                acc = fmaf(r, r, acc);
            }
            {
                float s = ctr.x + ctr.z + up.y + dn.y;
                float r = fmaf(s, a, fmaf(t.y + nf.y, -kdt, ctr.y * k2));
                acc = fmaf(r, r, acc);
            }
            {
                float s = ctr.y + ctr.w + up.z + dn.z;
                float r = fmaf(s, a, fmaf(t.z + nf.z, -kdt, ctr.z * k2));
                acc = fmaf(r, r, acc);
            }
            {
                float s = ctr.z + cr + up.w + dn.w;
                float r = fmaf(s, a, fmaf(t.w + nf.w, -kdt, ctr.w * k2));
                acc = fmaf(r, r, acc);
            }
        }

        // Roll planes (full unroll -> register renaming, no moves).
        #pragma unroll
        for (int i = 0; i < YB_; ++i) tm[i] = c[i + 1];
        #pragma unroll
        for (int j = 0; j < YB_ + 2; ++j) c[j] = nn[j];
        pn += PS_;
    }
    return acc;
}

__global__ __launch_bounds__(NTHREADS, 4)
void pinn_residual_partial(const float* __restrict__ u, float* __restrict__ partial) {
    const int lane = threadIdx.x & 63;
    const int w    = threadIdx.x >> 6;
    const int wid  = blockIdx.x * 4 + w;           // 0..4095
    const int ys = wid & (NSTRIP - 1);             // strip fastest: block = 16 consec y
    const int tc = (wid >> 6) & (TCHUNKS - 1);
    const int b  = wid >> 9;
    const int t0 = tc * 8;

    float s;
    if (tc < TCHUNKS - 1) s = strip_accum<8>(u, b, ys, t0, lane);
    else                  s = strip_accum<6>(u, b, ys, t0, lane);

    #pragma unroll
    for (int off = 32; off > 0; off >>= 1)
        s += __shfl_down(s, off, 64);

    __shared__ float lds[NTHREADS / 64];
    if (lane == 0) lds[w] = s;
    __syncthreads();
    if (threadIdx.x == 0) {
        float bs = 0.0f;
        #pragma unroll
        for (int q = 0; q < NTHREADS / 64; ++q) bs += lds[q];
        partial[blockIdx.x] = bs;   // every slot written every launch
    }
}

__global__ __launch_bounds__(NTHREADS)
void pinn_finalize(const float* __restrict__ partial, float* __restrict__ out) {
    float s = 0.0f;
    for (int i = threadIdx.x; i < NBLOCKS; i += NTHREADS)
        s += partial[i];
    #pragma unroll
    for (int off = 32; off > 0; off >>= 1)
        s += __shfl_down(s, off, 64);
    __shared__ float lds[NTHREADS / 64];
    int lane = threadIdx.x & 63;
    int wid  = threadIdx.x >> 6;
    if (lane == 0) lds[wid] = s;
    __syncthreads();
    if (threadIdx.x == 0) {
        float bs = 0.0f;
        #pragma unroll
        for (int q = 0; q < NTHREADS / 64; ++q) bs += lds[q];
        out[0] = sqrtf(bs);
    }
}

extern "C" void kernel_launch(void* const* d_in, const int* in_sizes, int n_in,
                              void* d_out, int out_size, void* d_ws, size_t ws_size,
                              hipStream_t stream) {
    const float* u = (const float*)d_in[0];
    float* partial = (float*)d_ws;              // NBLOCKS floats = 4 KiB scratch
    float* out     = (float*)d_out;

    pinn_residual_partial<<<NBLOCKS, NTHREADS, 0, stream>>>(u, partial);
    pinn_finalize<<<1, NTHREADS, 0, stream>>>(partial, out);
}